// Round 1
// baseline (1077.140 us; speedup 1.0000x reference)
//
#include <hip/hip_runtime.h>
#include <hip/hip_bf16.h>

// Problem constants (from reference): N=100000, D_IN=256, C=4, D_C=32, E=1.6e6
#define D_IN 256
#define D_OUT 128   // C * D_C
#define D_C 32
#define NUM_C 4

// ---- Kernel 1: transpose W [256][128] -> Wt [128][256] -------------------
__global__ void transpose_w_kernel(const float* __restrict__ W, float* __restrict__ Wt) {
    int t = blockIdx.x * blockDim.x + threadIdx.x;   // 0 .. 32767
    if (t >= D_IN * D_OUT) return;
    int k   = t >> 7;     // t / 128
    int col = t & 127;    // t % 128
    Wt[col * D_IN + k] = W[t];
}

// ---- Kernel 2: GEMM tmp[N][128] = x[N][256] @ W[256][128] ----------------
// 32 rows per block, 256 threads, each thread computes 4 rows x 4 cols.
__global__ __launch_bounds__(256) void gemm_kernel(const float* __restrict__ x,
                                                   const float* __restrict__ Wt,
                                                   float* __restrict__ tmp,
                                                   int Nrows) {
    __shared__ float xs[32][D_IN];   // 32 KiB
    const int t    = threadIdx.x;
    const int brow = blockIdx.x * 32;

    // Stage 32x256 x-tile (8192 floats = 2048 float4, 8 per thread, coalesced)
    if (brow + 32 <= Nrows) {
        const float4* xg  = reinterpret_cast<const float4*>(x + (size_t)brow * D_IN);
        float4*       xs4 = reinterpret_cast<float4*>(&xs[0][0]);
        #pragma unroll
        for (int i = 0; i < 8; ++i) xs4[i * 256 + t] = xg[i * 256 + t];
    } else {
        // guarded tail path (not hit for N=100000, kept for safety)
        for (int idx = t; idx < 32 * D_IN; idx += 256) {
            int r = idx >> 8, k = idx & 255;
            xs[r][k] = (brow + r < Nrows) ? x[(size_t)(brow + r) * D_IN + k] : 0.0f;
        }
    }
    __syncthreads();

    const int lane = t & 31;    // col group base
    const int rg   = t >> 5;    // 0..7 -> rows rg*4 .. rg*4+3
    float acc[4][4] = {};

    for (int k = 0; k < D_IN; k += 4) {
        float4 xv[4];
        #pragma unroll
        for (int r = 0; r < 4; ++r)
            xv[r] = *reinterpret_cast<const float4*>(&xs[rg * 4 + r][k]);
        #pragma unroll
        for (int cc = 0; cc < 4; ++cc) {
            const int col = lane + cc * 32;
            float4 wv = *reinterpret_cast<const float4*>(&Wt[(size_t)col * D_IN + k]);
            #pragma unroll
            for (int r = 0; r < 4; ++r) {
                acc[r][cc] += xv[r].x * wv.x;
                acc[r][cc] += xv[r].y * wv.y;
                acc[r][cc] += xv[r].z * wv.z;
                acc[r][cc] += xv[r].w * wv.w;
            }
        }
    }

    #pragma unroll
    for (int r = 0; r < 4; ++r) {
        const int row = brow + rg * 4 + r;
        if (row < Nrows) {
            #pragma unroll
            for (int cc = 0; cc < 4; ++cc)
                tmp[(size_t)row * D_OUT + lane + cc * 32] = acc[r][cc];
        }
    }
}

// ---- Kernel 3: edge scatter with atomics ---------------------------------
// One 32-lane group per edge (8 edges per 256-thread block).
// out[r][c*32+f] += tmp[col][c*32+f] * v
__global__ __launch_bounds__(256) void scatter_kernel(const int* __restrict__ rows,
                                                      const int* __restrict__ cols,
                                                      const float* __restrict__ vals,
                                                      const float* __restrict__ tmp,
                                                      float* __restrict__ out,
                                                      long long totalEdges, int E) {
    long long gid = (long long)blockIdx.x * 8 + (threadIdx.x >> 5);
    if (gid >= totalEdges) return;
    const int lane = threadIdx.x & 31;

    // class index without 64-bit divide
    const long long e1 = E, e2 = 2LL * E, e3 = 3LL * E;
    int c = (gid >= e3) ? 3 : (gid >= e2) ? 2 : (gid >= e1) ? 1 : 0;

    const int   r  = rows[gid];
    const int   cl = cols[gid];
    const float v  = vals[gid];

    const float tv = tmp[(size_t)cl * D_OUT + c * D_C + lane];
    atomicAdd(&out[(size_t)r * D_OUT + c * D_C + lane], tv * v);
}

// ---- Kernel 4: in-place relu ---------------------------------------------
__global__ void relu_kernel(float* __restrict__ out, int n4) {
    int i = blockIdx.x * blockDim.x + threadIdx.x;
    if (i < n4) {
        float4 v = reinterpret_cast<float4*>(out)[i];
        v.x = fmaxf(v.x, 0.0f);
        v.y = fmaxf(v.y, 0.0f);
        v.z = fmaxf(v.z, 0.0f);
        v.w = fmaxf(v.w, 0.0f);
        reinterpret_cast<float4*>(out)[i] = v;
    }
}

extern "C" void kernel_launch(void* const* d_in, const int* in_sizes, int n_in,
                              void* d_out, int out_size, void* d_ws, size_t ws_size,
                              hipStream_t stream) {
    const float* x    = (const float*)d_in[0];
    const float* W    = (const float*)d_in[1];
    const int*   rows = (const int*)d_in[2];
    const int*   cols = (const int*)d_in[3];
    const float* vals = (const float*)d_in[4];
    float* out = (float*)d_out;

    const int N  = in_sizes[0] / D_IN;        // 100000
    const long long CE = in_sizes[2];          // C * E = 6.4e6
    const int E  = (int)(CE / NUM_C);

    // workspace layout: tmp [N*128] floats, then Wt [128*256] floats
    float* tmp = (float*)d_ws;
    float* Wt  = tmp + (size_t)N * D_OUT;

    // zero the accumulator (harness poisons d_out before timing)
    hipMemsetAsync(d_out, 0, (size_t)out_size * sizeof(float), stream);

    transpose_w_kernel<<<(D_IN * D_OUT + 255) / 256, 256, 0, stream>>>(W, Wt);

    const int gemmBlocks = (N + 31) / 32;
    gemm_kernel<<<gemmBlocks, 256, 0, stream>>>(x, Wt, tmp, N);

    const long long nGroups = CE;
    const int scatterBlocks = (int)((nGroups + 7) / 8);
    scatter_kernel<<<scatterBlocks, 256, 0, stream>>>(rows, cols, vals, tmp, out, CE, E);

    const int n4 = out_size / 4;
    relu_kernel<<<(n4 + 255) / 256, 256, 0, stream>>>(out, n4);
}

// Round 2
// 1000.566 us; speedup vs baseline: 1.0765x; 1.0765x over previous
//
#include <hip/hip_runtime.h>
#include <hip/hip_bf16.h>

// Problem constants: N=100000, D_IN=256, C=4, D_C=32, E=1.6e6
#define D_IN 256
#define D_OUT 128   // C * D_C
#define D_C 32
#define NUM_C 4

// ---- GEMM: tmp[N][128] = x[N][256] @ W[256][128] -------------------------
// 64-row x 128-col tile per 256-thread block; W staged in natural [k][col]
// layout (no transpose needed). Each thread: 8 rows x 4 consecutive cols.
__global__ __launch_bounds__(256) void gemm_kernel(const float* __restrict__ x,
                                                   const float* __restrict__ W,
                                                   float* __restrict__ tmp,
                                                   int Nrows) {
    __shared__ float xs[64][68];    // [row][k], pad 68 keeps float4 alignment + breaks banks
    __shared__ float ws[32][128];   // [k][col]
    const int t    = threadIdx.x;
    const int brow = blockIdx.x * 64;
    const int lane = t & 31;
    const int rg   = t >> 5;        // 0..7
    const int row0 = rg * 8;
    const int col0 = lane * 4;

    float acc[8][4] = {};

    for (int k0 = 0; k0 < D_IN; k0 += 32) {
        // stage x: 64 rows x 32 k = 512 float4; 2 per thread
        #pragma unroll
        for (int s = 0; s < 2; ++s) {
            int i = t + 256 * s;
            int r = i >> 3, kq = i & 7;
            float4 v = make_float4(0.f, 0.f, 0.f, 0.f);
            if (brow + r < Nrows)
                v = *reinterpret_cast<const float4*>(&x[(size_t)(brow + r) * D_IN + k0 + kq * 4]);
            *reinterpret_cast<float4*>(&xs[r][kq * 4]) = v;
        }
        // stage W slab: 32 k x 128 cols = 4096 floats = 1024 float4; 4 per thread
        const float4* wg  = reinterpret_cast<const float4*>(W + (size_t)k0 * D_OUT);
        float4*       ws4 = reinterpret_cast<float4*>(&ws[0][0]);
        #pragma unroll
        for (int s = 0; s < 4; ++s) ws4[t + 256 * s] = wg[t + 256 * s];
        __syncthreads();

        #pragma unroll
        for (int kk = 0; kk < 32; kk += 4) {
            float4 xv[8];
            #pragma unroll
            for (int r = 0; r < 8; ++r)
                xv[r] = *reinterpret_cast<const float4*>(&xs[row0 + r][kk]);  // broadcast
            #pragma unroll
            for (int q = 0; q < 4; ++q) {
                float4 wv = *reinterpret_cast<const float4*>(&ws[kk + q][col0]);
                #pragma unroll
                for (int r = 0; r < 8; ++r) {
                    float xsc = reinterpret_cast<const float*>(&xv[r])[q];
                    acc[r][0] = fmaf(xsc, wv.x, acc[r][0]);
                    acc[r][1] = fmaf(xsc, wv.y, acc[r][1]);
                    acc[r][2] = fmaf(xsc, wv.z, acc[r][2]);
                    acc[r][3] = fmaf(xsc, wv.w, acc[r][3]);
                }
            }
        }
        __syncthreads();
    }

    #pragma unroll
    for (int r = 0; r < 8; ++r) {
        int row = brow + row0 + r;
        if (row < Nrows)
            *reinterpret_cast<float4*>(&tmp[(size_t)row * D_OUT + col0]) =
                make_float4(acc[r][0], acc[r][1], acc[r][2], acc[r][3]);
    }
}

// ---- CSR build: histogram ------------------------------------------------
__global__ void hist_kernel(const int* __restrict__ rows, int* __restrict__ cnt,
                            int CE, int E, int N) {
    int e = blockIdx.x * 256 + threadIdx.x;
    if (e >= CE) return;
    int c = (e >= 3 * E) ? 3 : (e >= 2 * E) ? 2 : (e >= E) ? 1 : 0;
    atomicAdd(&cnt[c * N + rows[e]], 1);
}

// ---- scan phase A: per-block (2048-elem) sums ----------------------------
__global__ __launch_bounds__(256) void scanA_kernel(const int* __restrict__ cnt,
                                                    int* __restrict__ bsum, int M) {
    __shared__ int sd[256];
    int t = threadIdx.x;
    int base = blockIdx.x * 2048;
    int s = 0;
    #pragma unroll
    for (int i = 0; i < 8; ++i) {
        int idx = base + t + i * 256;
        if (idx < M) s += cnt[idx];
    }
    sd[t] = s; __syncthreads();
    for (int off = 128; off > 0; off >>= 1) {
        if (t < off) sd[t] += sd[t + off];
        __syncthreads();
    }
    if (t == 0) bsum[blockIdx.x] = sd[0];
}

// ---- scan phase B: exclusive scan of block sums (nb <= 1024) -------------
__global__ __launch_bounds__(1024) void scanB_kernel(int* __restrict__ bsum, int nb) {
    __shared__ int sd[1024];
    int t = threadIdx.x;
    int v = (t < nb) ? bsum[t] : 0;
    sd[t] = v; __syncthreads();
    for (int off = 1; off < 1024; off <<= 1) {
        int add = (t >= off) ? sd[t - off] : 0;
        __syncthreads();
        sd[t] += add;
        __syncthreads();
    }
    if (t < nb) bsum[t] = sd[t] - v;   // exclusive
}

// ---- scan phase C: within-block exclusive scan + base; writes start+heads -
__global__ __launch_bounds__(256) void scanC_kernel(const int* __restrict__ cnt,
                                                    const int* __restrict__ bsum,
                                                    int* __restrict__ start,
                                                    int* __restrict__ heads, int M) {
    __shared__ int sd[256];
    int t = threadIdx.x;
    int base = blockIdx.x * 2048 + t * 8;
    int loc[8];
    int s = 0;
    #pragma unroll
    for (int i = 0; i < 8; ++i) {
        loc[i] = (base + i < M) ? cnt[base + i] : 0;
        s += loc[i];
    }
    sd[t] = s; __syncthreads();
    for (int off = 1; off < 256; off <<= 1) {
        int add = (t >= off) ? sd[t - off] : 0;
        __syncthreads();
        sd[t] += add;
        __syncthreads();
    }
    int run = bsum[blockIdx.x] + (sd[t] - s);
    #pragma unroll
    for (int i = 0; i < 8; ++i) {
        if (base + i < M) { start[base + i] = run; heads[base + i] = run; }
        run += loc[i];
    }
}

// ---- CSR build: placement scatter ----------------------------------------
__global__ void build_kernel(const int* __restrict__ rows, const int* __restrict__ cols,
                             const float* __restrict__ vals, int* __restrict__ heads,
                             int2* __restrict__ cv, int CE, int E, int N) {
    int e = blockIdx.x * 256 + threadIdx.x;
    if (e >= CE) return;
    int c = (e >= 3 * E) ? 3 : (e >= 2 * E) ? 2 : (e >= E) ? 1 : 0;
    int pos = atomicAdd(&heads[c * N + rows[e]], 1);
    cv[pos] = make_int2(cols[e], __float_as_int(vals[e]));
}

// ---- pull: one 32-lane group per (class,row); fused ReLU, no atomics -----
__global__ __launch_bounds__(256) void pull_kernel(const int* __restrict__ start,
                                                   const int* __restrict__ cnt,
                                                   const int2* __restrict__ cv,
                                                   const float* __restrict__ tmp,
                                                   float* __restrict__ out,
                                                   int N, int M) {
    int p = blockIdx.x * 8 + (threadIdx.x >> 5);
    if (p >= M) return;
    const int lane = threadIdx.x & 31;
    int c = p / N;
    int r = p - c * N;
    int s = start[p];
    int n = cnt[p];
    const int cofs = c * D_C + lane;

    float acc = 0.f;
    int i = 0;
    for (; i + 1 < n; i += 2) {
        int2 e0 = cv[s + i];
        int2 e1 = cv[s + i + 1];
        acc = fmaf(__int_as_float(e0.y), tmp[e0.x * D_OUT + cofs], acc);
        acc = fmaf(__int_as_float(e1.y), tmp[e1.x * D_OUT + cofs], acc);
    }
    if (i < n) {
        int2 e0 = cv[s + i];
        acc = fmaf(__int_as_float(e0.y), tmp[e0.x * D_OUT + cofs], acc);
    }
    out[(size_t)r * D_OUT + cofs] = fmaxf(acc, 0.f);
}

// ---- fallback (ws too small): atomic scatter + relu ----------------------
__global__ __launch_bounds__(256) void scatter_kernel(const int* __restrict__ rows,
                                                      const int* __restrict__ cols,
                                                      const float* __restrict__ vals,
                                                      const float* __restrict__ tmp,
                                                      float* __restrict__ out,
                                                      long long totalEdges, int E) {
    long long gid = (long long)blockIdx.x * 8 + (threadIdx.x >> 5);
    if (gid >= totalEdges) return;
    const int lane = threadIdx.x & 31;
    const long long e1 = E, e2 = 2LL * E, e3 = 3LL * E;
    int c = (gid >= e3) ? 3 : (gid >= e2) ? 2 : (gid >= e1) ? 1 : 0;
    const int   r  = rows[gid];
    const int   cl = cols[gid];
    const float v  = vals[gid];
    const float tv = tmp[(size_t)cl * D_OUT + c * D_C + lane];
    atomicAdd(&out[(size_t)r * D_OUT + c * D_C + lane], tv * v);
}

__global__ void relu_kernel(float* __restrict__ out, int n4) {
    int i = blockIdx.x * blockDim.x + threadIdx.x;
    if (i < n4) {
        float4 v = reinterpret_cast<float4*>(out)[i];
        v.x = fmaxf(v.x, 0.f); v.y = fmaxf(v.y, 0.f);
        v.z = fmaxf(v.z, 0.f); v.w = fmaxf(v.w, 0.f);
        reinterpret_cast<float4*>(out)[i] = v;
    }
}

extern "C" void kernel_launch(void* const* d_in, const int* in_sizes, int n_in,
                              void* d_out, int out_size, void* d_ws, size_t ws_size,
                              hipStream_t stream) {
    const float* x    = (const float*)d_in[0];
    const float* W    = (const float*)d_in[1];
    const int*   rows = (const int*)d_in[2];
    const int*   cols = (const int*)d_in[3];
    const float* vals = (const float*)d_in[4];
    float* out = (float*)d_out;

    const int N  = in_sizes[0] / D_IN;      // 100000
    const int CE = in_sizes[2];             // C * E = 6,400,000
    const int E  = CE / NUM_C;
    const int M  = NUM_C * N;               // 400,000 (class,row) pairs

    // workspace layout (16B aligned chunks)
    size_t off = 0;
    float* tmp = (float*)((char*)d_ws + off);  off += (size_t)N * D_OUT * 4;
    int*   cnt   = (int*)((char*)d_ws + off);  off += (size_t)M * 4;
    int*   startA= (int*)((char*)d_ws + off);  off += (size_t)M * 4;
    int*   heads = (int*)((char*)d_ws + off);  off += (size_t)M * 4;
    int*   bsum  = (int*)((char*)d_ws + off);  off += 4096;
    off = (off + 15) & ~(size_t)15;
    int2*  cv    = (int2*)((char*)d_ws + off); off += (size_t)CE * 8;
    const bool csr_ok = (off <= ws_size);

    const int gemmBlocks = (N + 63) / 64;
    gemm_kernel<<<gemmBlocks, 256, 0, stream>>>(x, W, tmp, N);

    if (csr_ok) {
        hipMemsetAsync(cnt, 0, (size_t)M * 4, stream);
        const int edgeBlocks = (CE + 255) / 256;
        hist_kernel<<<edgeBlocks, 256, 0, stream>>>(rows, cnt, CE, E, N);
        const int nb = (M + 2047) / 2048;
        scanA_kernel<<<nb, 256, 0, stream>>>(cnt, bsum, M);
        scanB_kernel<<<1, 1024, 0, stream>>>(bsum, nb);
        scanC_kernel<<<nb, 256, 0, stream>>>(cnt, bsum, startA, heads, M);
        build_kernel<<<edgeBlocks, 256, 0, stream>>>(rows, cols, vals, heads, cv, CE, E, N);
        const int pullBlocks = (M + 7) / 8;
        pull_kernel<<<pullBlocks, 256, 0, stream>>>(startA, cnt, cv, tmp, out, N, M);
    } else {
        // fallback: atomic push path
        hipMemsetAsync(d_out, 0, (size_t)out_size * sizeof(float), stream);
        const int scatterBlocks = (CE + 7) / 8;
        scatter_kernel<<<scatterBlocks, 256, 0, stream>>>(rows, cols, vals, tmp, out, CE, E);
        const int n4 = out_size / 4;
        relu_kernel<<<(n4 + 255) / 256, 256, 0, stream>>>(out, n4);
    }
}